// Round 5
// baseline (512.516 us; speedup 1.0000x reference)
//
#include <hip/hip_runtime.h>

// BoxCrossCategoryLoss: streaming row-wise loss over 6 x (N,2) f32 arrays.
// int index inputs are unused by the reference (recipes are constants).
//
// R8: float2 taps (1 row/thread/tap) -> ring-of-2 fits in 64 VGPRs.
// Evidence trail: R4 (coupled loads, VGPR 56, 32 waves/CU) = 2.74 TB/s read;
// R7 (decoupled ring-2 @ float4, VGPR 96, spill-free but only 5 waves/EU)
// = 2.56 TB/s. Decoupling traded occupancy away because ring-2@float4 needs
// ~83 regs. Shrinking the tap to float2 (12 regs/slot, ~30 temps) is the
// ONLY config with BOTH a decoupled pipeline AND 8 waves/EU. If this also
// pins at ~2.7 TB/s read, that's the pattern service ceiling (384 MB /
// 2.7 TB/s = 142 us) and we're done; if latency*concurrency was the limit,
// expect ~90-115 us.

#define LOG2E 1.4426950408889634f
#define LN2   0.6931471805599453f

__device__ __forceinline__ float fexp2(float x) { return __builtin_amdgcn_exp2f(x); }
__device__ __forceinline__ float flog2(float x) { return __builtin_amdgcn_logf(x); }
__device__ __forceinline__ float relu_(float x) { return fmaxf(x, 0.0f); }

// Per-row loss in LOG2 UNITS. Raw natural-log inputs (strictly negative).
__device__ __forceinline__ float row_loss_l2(
    float a0, float a1, float b0, float b1,
    float c0, float c1, float d0, float d1,
    float e0, float e1, float f0, float f1)
{
    // scaled inputs (log2 units) — also the exp2 arguments
    float a0s = a0 * LOG2E, a1s = a1 * LOG2E;
    float b0s = b0 * LOG2E, b1s = b1 * LOG2E;
    float c0s = c0 * LOG2E, c1s = c1 * LOG2E;
    float d0s = d0 * LOG2E, d1s = d1 * LOG2E;
    float e0s = e0 * LOG2E, e1s = e1 * LOG2E;
    float f0s = f0 * LOG2E, f1s = f1 * LOG2E;

    // u = exp(x) via hardware exp2; w = 1 - u
    float ua0 = fexp2(a0s), ub0 = fexp2(b0s), uc0 = fexp2(c0s), ud0 = fexp2(d0s);
    float ue0 = fexp2(e0s), uf0 = fexp2(f0s);
    float ua1 = fexp2(a1s), ub1 = fexp2(b1s), uc1 = fexp2(c1s), ud1 = fexp2(d1s);
    float ue1 = fexp2(e1s), uf1 = fexp2(f1s);

    float wa0 = 1.0f - ua0, wb0 = 1.0f - ub0, wc0 = 1.0f - uc0, wd0 = 1.0f - ud0;
    float we0 = 1.0f - ue0, wf0 = 1.0f - uf0;
    float wa1 = 1.0f - ua1, wb1 = 1.0f - ub1, wc1 = 1.0f - uc1, wd1 = 1.0f - ud1;
    float we1 = 1.0f - ue1, wf1 = 1.0f - uf1;

    // l = log2(1 - exp(x)) via hardware log2 (10 needed individually)
    float la0 = flog2(wa0), lb0 = flog2(wb0), lc0 = flog2(wc0), ld0 = flog2(wd0);
    float la1 = flog2(wa1), lb1 = flog2(wb1), lc1 = flog2(wc1), ld1 = flog2(wd1);
    float le1 = flog2(we1), lf1 = flog2(wf1);

    // LACk = log1mexp(pAC[k][:,0]) in log2 units:
    float LAC0 = flog2(fmaf(-ue0, wf0, 1.0f));
    float LAC1 = flog2(fmaf(-we0, uf0, 1.0f));
    float LAC2 = flog2(fmaf(-ue0, uf0, 1.0f));

    // p[k] = [v1+l2, l1+v2, v1+v2, l1+l2]  (log2 units)
    float AB00 = a0s + lb0, AB10 = la0 + b0s, AB20 = a0s + b0s;
    float AB01 = a1s + lb1, AB11 = la1 + b1s, AB21 = a1s + b1s, AB31 = la1 + lb1;
    float BC00 = c0s + ld0, BC10 = lc0 + d0s, BC20 = c0s + d0s;
    float BC01 = c1s + ld1, BC11 = lc1 + d1s, BC21 = c1s + d1s, BC31 = lc1 + ld1;
    float AC01 = e1s + lf1, AC11 = le1 + f1s, AC21 = e1s + f1s, AC31 = le1 + lf1;

    // 14 unique AB+BC sums shared across the 36 terms.
    float s1  = AB00 + BC01, s2  = AB00 + BC21, s3  = AB10 + BC11, s4  = AB10 + BC21;
    float s5  = AB20 + BC01, s6  = AB20 + BC11, s7  = AB20 + BC21, s8  = AB20 + BC31;
    float s9  = AB01 + BC00, s10 = AB01 + BC20, s11 = AB11 + BC10, s12 = AB11 + BC20;
    float s13 = AB21 + BC20, s14 = AB31 + BC20;

    // Two independent accumulator chains for add ILP.
    float p = 0.0f, q = 0.0f;
    // LOSS_RECIPE (14 terms)
    p += relu_(s1 - AC01) + relu_(s2 - AC01) + relu_(s3 - AC11) + relu_(s4 - AC11);
    q += relu_(s5 - AC01) + relu_(s6 - AC11) + relu_(s7 - AC21) + relu_(s8 - AC31);
    p += relu_(s9 - AC01) + relu_(s10 - AC01) + relu_(s11 - AC11) + relu_(s12 - AC11);
    q += relu_(s13 - AC21) + relu_(s14 - AC31);
    // NEG_LOSS_RECIPE (22 terms)
    p += relu_(s1 - LAC1) + relu_(s1 - LAC2) + relu_(s2 - LAC1) + relu_(s2 - LAC2);
    q += relu_(s3 - LAC0) + relu_(s3 - LAC2) + relu_(s4 - LAC0) + relu_(s4 - LAC2);
    p += relu_(s5 - LAC1) + relu_(s5 - LAC2) + relu_(s6 - LAC0) + relu_(s6 - LAC2);
    q += relu_(s9 - LAC1) + relu_(s9 - LAC2) + relu_(s10 - LAC1) + relu_(s10 - LAC2);
    p += relu_(s11 - LAC0) + relu_(s11 - LAC2) + relu_(s12 - LAC0) + relu_(s12 - LAC2);
    q += relu_(s8 - LAC2) + relu_(s14 - LAC2);
    return p + q;  // log2 units
}

// One row (float2 from each of the 6 arrays): 12 buffer regs per slot.
struct Seg2 {
    float2 ab, ba, bc, cb, ac, ca;
};

__device__ __forceinline__ float row_loss_seg(const Seg2& s)
{
    return row_loss_l2(s.ab.x, s.ab.y, s.ba.x, s.ba.y, s.bc.x, s.bc.y,
                       s.cb.x, s.cb.y, s.ac.x, s.ac.y, s.ca.x, s.ca.y);
}

__global__ __launch_bounds__(256)
__attribute__((amdgpu_waves_per_eu(6, 8)))
void box_loss_kernel(
    const float* __restrict__ AB, const float* __restrict__ BA,
    const float* __restrict__ BC, const float* __restrict__ CB,
    const float* __restrict__ AC, const float* __restrict__ CA,
    float* __restrict__ out, unsigned nElems)
{
    const unsigned nE = nElems;
    // 32-bit element offsets -> saddr-form global_load_dwordx2.
    const unsigned T = (unsigned)gridDim.x * blockDim.x * 2u;  // tap stride
    unsigned t = ((unsigned)blockIdx.x * blockDim.x + threadIdx.x) * 2u;

    const unsigned nT = (nE + T - 1u) / T;      // taps per thread
    const int pairs = (int)((nT + 1u) / 2u);    // processed taps = 2*pairs

    // Branch-free bounds: clamp OOB offset to 0 (valid data), zero the mask.
    #define LOAD_SEG(dst, msk, base)                        \
        do {                                                \
            bool v_ = ((base) + 2u) <= nE;                  \
            unsigned a_ = v_ ? (base) : 0u;                 \
            (msk) = v_ ? 1.0f : 0.0f;                       \
            (dst).ab = *(const float2*)(AB + a_);           \
            (dst).ba = *(const float2*)(BA + a_);           \
            (dst).bc = *(const float2*)(BC + a_);           \
            (dst).cb = *(const float2*)(CB + a_);           \
            (dst).ac = *(const float2*)(AC + a_);           \
            (dst).ca = *(const float2*)(CA + a_);           \
        } while (0)

    Seg2 X, Y;
    float mX, mY;

    // Prologue: fill both ring slots (12 dwordx2 loads in flight).
    LOAD_SEG(X, mX, t); t += T;
    LOAD_SEG(Y, mY, t); t += T;
    __builtin_amdgcn_sched_barrier(0);

    float acc = 0.0f;
    // Steady state: consume one slot, immediately re-issue its 6 loads for
    // the tap 2 slots ahead; sched_barrier(0) pins the issue above the next
    // slot's compute so each slot's load->use distance is one full compute
    // phase (compiler waits vmcnt(6), never vmcnt(0)).
    for (int r = 0; r < pairs - 1; ++r) {
        acc += mX * row_loss_seg(X);
        LOAD_SEG(X, mX, t); t += T;
        __builtin_amdgcn_sched_barrier(0);

        acc += mY * row_loss_seg(Y);
        LOAD_SEG(Y, mY, t); t += T;
        __builtin_amdgcn_sched_barrier(0);
    }
    // Epilogue: drain the ring (no further loads, no junk traffic).
    acc += mX * row_loss_seg(X);
    acc += mY * row_loss_seg(Y);
    #undef LOAD_SEG

    acc *= LN2;  // convert log2-unit total back to natural units

    // wave64 butterfly reduce
    #pragma unroll
    for (int off = 32; off > 0; off >>= 1)
        acc += __shfl_down(acc, off, 64);

    __shared__ float wsum[4];
    const int lane = threadIdx.x & 63;
    const int wid  = threadIdx.x >> 6;
    if (lane == 0) wsum[wid] = acc;
    __syncthreads();
    if (threadIdx.x == 0) {
        float s = wsum[0] + wsum[1] + wsum[2] + wsum[3];
        atomicAdd(out, s);
    }
}

extern "C" void kernel_launch(void* const* d_in, const int* in_sizes, int n_in,
                              void* d_out, int out_size, void* d_ws, size_t ws_size,
                              hipStream_t stream) {
    const float* AB = (const float*)d_in[0];  // vol_AB
    const float* BA = (const float*)d_in[1];  // vol_BA
    const float* BC = (const float*)d_in[2];  // vol_BC
    const float* CB = (const float*)d_in[3];  // vol_CB
    const float* AC = (const float*)d_in[4];  // vol_AC
    const float* CA = (const float*)d_in[5];  // vol_CA
    // d_in[6..8] (xy/yz/xz rel ids) are unused by the reference.

    const unsigned nElems = (unsigned)in_sizes[0];  // N*2 = 16M
    const int block = 256;
    // grid 2048 = 8 blocks/CU of work; at VGPR<=64 all 8 are resident
    // (32 waves/CU). Tap stride = 2048*256*2 = 1,048,576 elems -> 16
    // taps/thread = 8 ring rounds (last tap partially masked).
    const int grid = 2048;

    // d_out is poisoned with 0xAA before every timed launch — zero it.
    hipMemsetAsync(d_out, 0, (size_t)out_size * sizeof(float), stream);
    box_loss_kernel<<<grid, block, 0, stream>>>(AB, BA, BC, CB, AC, CA,
                                                (float*)d_out, nElems);
}

// Round 7
// 442.250 us; speedup vs baseline: 1.1589x; 1.1589x over previous
//
#include <hip/hip_runtime.h>

// BoxCrossCategoryLoss: streaming row-wise loss over 6 x (N,2) f32 arrays.
// int index inputs are unused by the reference (recipes are constants).
//
// R9 (resubmit — previous round died with the same opaque container-infra
// signature as R1, which on resubmission ran fine; audit found no deadlock/
// fault path: uniform barrier counts, exact vmcnt bookkeeping, all-valid
// tiles at N*2=15625*1024, wave-uniform LDS dests).
//
// LDS-staged streaming via global_load_lds + counted vmcnt (T3/T4).
// Evidence: every register-resident prefetch attempt failed — R5/R6/R8
// spilled catastrophically (VGPR clamped to 64/64/40, 350-614 MB scratch),
// R7 was clean (VGPR 96) but taxed occupancy; all land at 2.5-2.7 TB/s
// useful read. FETCH=187MB => only ~30us of real HBM time; the machine is
// idle ~75% => concurrency, not bandwidth, is the limiter, and the VGPR
// file is the wrong place for the prefetch queue. This version keeps
// in-flight bytes in the vmcnt queue + LDS instead:
//   - triple-buffered LDS: 3 bufs x (6 arrays x 4 waves x 1 KB) = 72 KB
//   - per wave per tile: 6 x global_load_lds_dwordx4 (linear dest,
//     wave-uniform base + lane*16 — the HW-required layout)
//   - loop: s_waitcnt vmcnt(6) [tile i landed, i+1 flying] -> raw s_barrier
//     (NO vmcnt(0) drain -> loads stay in flight across barriers) ->
//     issue tile i+2 into the buffer freed by this barrier -> compute i.
//   - dummy clamped issues in the tail keep vmcnt arithmetic exact.
// 12 KB/wave in flight x 8 waves/CU = 96 KB/CU vs ~20 KB needed at ~2000cy.

#define LOG2E 1.4426950408889634f
#define LN2   0.6931471805599453f

__device__ __forceinline__ float fexp2(float x) { return __builtin_amdgcn_exp2f(x); }
__device__ __forceinline__ float flog2(float x) { return __builtin_amdgcn_logf(x); }
__device__ __forceinline__ float relu_(float x) { return fmaxf(x, 0.0f); }

// Async global->LDS, 16 B per lane. Dest must be the wave-uniform chunk
// base; HW writes base + lane*16. Source is per-lane.
__device__ __forceinline__ void stage16(const float* g, float* l)
{
    __builtin_amdgcn_global_load_lds(
        (const __attribute__((address_space(1))) void*)g,
        (__attribute__((address_space(3))) void*)l,
        16, 0, 0);
}

// Per-row loss in LOG2 UNITS. Raw natural-log inputs (strictly negative).
__device__ __forceinline__ float row_loss_l2(
    float a0, float a1, float b0, float b1,
    float c0, float c1, float d0, float d1,
    float e0, float e1, float f0, float f1)
{
    // scaled inputs (log2 units) — also the exp2 arguments
    float a0s = a0 * LOG2E, a1s = a1 * LOG2E;
    float b0s = b0 * LOG2E, b1s = b1 * LOG2E;
    float c0s = c0 * LOG2E, c1s = c1 * LOG2E;
    float d0s = d0 * LOG2E, d1s = d1 * LOG2E;
    float e0s = e0 * LOG2E, e1s = e1 * LOG2E;
    float f0s = f0 * LOG2E, f1s = f1 * LOG2E;

    // u = exp(x) via hardware exp2; w = 1 - u
    float ua0 = fexp2(a0s), ub0 = fexp2(b0s), uc0 = fexp2(c0s), ud0 = fexp2(d0s);
    float ue0 = fexp2(e0s), uf0 = fexp2(f0s);
    float ua1 = fexp2(a1s), ub1 = fexp2(b1s), uc1 = fexp2(c1s), ud1 = fexp2(d1s);
    float ue1 = fexp2(e1s), uf1 = fexp2(f1s);

    float wa0 = 1.0f - ua0, wb0 = 1.0f - ub0, wc0 = 1.0f - uc0, wd0 = 1.0f - ud0;
    float we0 = 1.0f - ue0, wf0 = 1.0f - uf0;
    float wa1 = 1.0f - ua1, wb1 = 1.0f - ub1, wc1 = 1.0f - uc1, wd1 = 1.0f - ud1;
    float we1 = 1.0f - ue1, wf1 = 1.0f - uf1;

    // l = log2(1 - exp(x)) via hardware log2 (10 needed individually)
    float la0 = flog2(wa0), lb0 = flog2(wb0), lc0 = flog2(wc0), ld0 = flog2(wd0);
    float la1 = flog2(wa1), lb1 = flog2(wb1), lc1 = flog2(wc1), ld1 = flog2(wd1);
    float le1 = flog2(we1), lf1 = flog2(wf1);

    // LACk = log1mexp(pAC[k][:,0]) in log2 units:
    float LAC0 = flog2(fmaf(-ue0, wf0, 1.0f));
    float LAC1 = flog2(fmaf(-we0, uf0, 1.0f));
    float LAC2 = flog2(fmaf(-ue0, uf0, 1.0f));

    // p[k] = [v1+l2, l1+v2, v1+v2, l1+l2]  (log2 units)
    float AB00 = a0s + lb0, AB10 = la0 + b0s, AB20 = a0s + b0s;
    float AB01 = a1s + lb1, AB11 = la1 + b1s, AB21 = a1s + b1s, AB31 = la1 + lb1;
    float BC00 = c0s + ld0, BC10 = lc0 + d0s, BC20 = c0s + d0s;
    float BC01 = c1s + ld1, BC11 = lc1 + d1s, BC21 = c1s + d1s, BC31 = lc1 + ld1;
    float AC01 = e1s + lf1, AC11 = le1 + f1s, AC21 = e1s + f1s, AC31 = le1 + lf1;

    // 14 unique AB+BC sums shared across the 36 terms.
    float s1  = AB00 + BC01, s2  = AB00 + BC21, s3  = AB10 + BC11, s4  = AB10 + BC21;
    float s5  = AB20 + BC01, s6  = AB20 + BC11, s7  = AB20 + BC21, s8  = AB20 + BC31;
    float s9  = AB01 + BC00, s10 = AB01 + BC20, s11 = AB11 + BC10, s12 = AB11 + BC20;
    float s13 = AB21 + BC20, s14 = AB31 + BC20;

    // Two independent accumulator chains for add ILP.
    float p = 0.0f, q = 0.0f;
    // LOSS_RECIPE (14 terms)
    p += relu_(s1 - AC01) + relu_(s2 - AC01) + relu_(s3 - AC11) + relu_(s4 - AC11);
    q += relu_(s5 - AC01) + relu_(s6 - AC11) + relu_(s7 - AC21) + relu_(s8 - AC31);
    p += relu_(s9 - AC01) + relu_(s10 - AC01) + relu_(s11 - AC11) + relu_(s12 - AC11);
    q += relu_(s13 - AC21) + relu_(s14 - AC31);
    // NEG_LOSS_RECIPE (22 terms)
    p += relu_(s1 - LAC1) + relu_(s1 - LAC2) + relu_(s2 - LAC1) + relu_(s2 - LAC2);
    q += relu_(s3 - LAC0) + relu_(s3 - LAC2) + relu_(s4 - LAC0) + relu_(s4 - LAC2);
    p += relu_(s5 - LAC1) + relu_(s5 - LAC2) + relu_(s6 - LAC0) + relu_(s6 - LAC2);
    q += relu_(s9 - LAC1) + relu_(s9 - LAC2) + relu_(s10 - LAC1) + relu_(s10 - LAC2);
    p += relu_(s11 - LAC0) + relu_(s11 - LAC2) + relu_(s12 - LAC0) + relu_(s12 - LAC2);
    q += relu_(s8 - LAC2) + relu_(s14 - LAC2);
    return p + q;  // log2 units
}

// Tile = 1024 elems (256 threads x float4). LDS layout (floats):
//   chunk(buf, arr, wave) at ((buf*6 + arr)*4 + wave) * 256, 1 KB each.
// Wave writes its chunk via stage16 (lane*16 auto-offset); thread reads
// back its own float4 at + lane*4 -> contiguous ds_read_b128, conflict-free.

__global__ __launch_bounds__(256) void box_loss_kernel(
    const float* __restrict__ AB, const float* __restrict__ BA,
    const float* __restrict__ BC, const float* __restrict__ CB,
    const float* __restrict__ AC, const float* __restrict__ CA,
    float* __restrict__ out, unsigned nElems)
{
    extern __shared__ __align__(16) float lds[];  // 3*6*4*256 floats = 72 KB

    const unsigned nE = nElems;
    const int tid  = threadIdx.x;
    const int wid  = tid >> 6;
    const int lane = tid & 63;
    const int G    = gridDim.x;
    const int bid  = blockIdx.x;
    const unsigned tOff = (unsigned)tid * 4u;       // elem offset within tile

    const int nT = (int)((nE + 1023u) / 1024u);     // total tiles
    int myCount  = (nT - bid + G - 1) / G;          // tiles for this block
    if (myCount < 1) myCount = 1;                    // safety (unreachable)
    const int lastI = myCount - 1;

    // Issue one tile's 6 staging loads for this wave into buffer `buf`.
    #define ISSUE(buf, tile)                                            \
        do {                                                            \
            unsigned e_ = (unsigned)(tile) * 1024u + tOff;              \
            unsigned a_ = (e_ + 4u <= nE) ? e_ : 0u;                    \
            float* lb_ = lds + (((buf) * 24) + wid) * 256;              \
            stage16(AB + a_, lb_ + 0 * 1024);                           \
            stage16(BA + a_, lb_ + 1 * 1024);                           \
            stage16(BC + a_, lb_ + 2 * 1024);                           \
            stage16(CB + a_, lb_ + 3 * 1024);                           \
            stage16(AC + a_, lb_ + 4 * 1024);                           \
            stage16(CA + a_, lb_ + 5 * 1024);                           \
        } while (0)

    // Prologue: fill the pipeline 2 tiles deep (12 loads in flight/wave).
    ISSUE(0, bid);
    ISSUE(1, (1 <= lastI) ? (bid + G) : bid);
    __builtin_amdgcn_sched_barrier(0);

    float acc = 0.0f;
    for (int i = 0; i < myCount; ++i) {
        // My 6 loads for tile i are the oldest; tile i+1's 6 stay in flight.
        asm volatile("s_waitcnt vmcnt(6)" ::: "memory");
        // All waves' tile-i data in LDS; all waves finished reading the
        // buffer (i+2)%3 (they computed tile i-1 from it before arriving).
        __builtin_amdgcn_s_barrier();
        __builtin_amdgcn_sched_barrier(0);

        // Refill the just-freed buffer with tile i+2 (clamped dummy in the
        // tail keeps the vmcnt count exact; its data is never read).
        {
            int j = i + 2;
            int tj = (j <= lastI) ? (bid + j * G) : (bid + lastI * G);
            ISSUE(j % 3, tj);
        }
        __builtin_amdgcn_sched_barrier(0);

        // Compute tile i from buffer i%3.
        {
            const float* lb = lds + ((i % 3) * 24 + wid) * 256 + lane * 4;
            float4 vab = *(const float4*)(lb + 0 * 1024);
            float4 vba = *(const float4*)(lb + 1 * 1024);
            float4 vbc = *(const float4*)(lb + 2 * 1024);
            float4 vcb = *(const float4*)(lb + 3 * 1024);
            float4 vac = *(const float4*)(lb + 4 * 1024);
            float4 vca = *(const float4*)(lb + 5 * 1024);

            unsigned e = (unsigned)(bid + i * G) * 1024u + tOff;
            float m = (e + 4u <= nE) ? 1.0f : 0.0f;

            acc += m * (row_loss_l2(vab.x, vab.y, vba.x, vba.y, vbc.x, vbc.y,
                                    vcb.x, vcb.y, vac.x, vac.y, vca.x, vca.y)
                      + row_loss_l2(vab.z, vab.w, vba.z, vba.w, vbc.z, vbc.w,
                                    vcb.z, vcb.w, vac.z, vac.w, vca.z, vca.w));
        }
    }
    #undef ISSUE
    // Drain the trailing dummy loads before reusing LDS for the reduction.
    asm volatile("s_waitcnt vmcnt(0)" ::: "memory");

    acc *= LN2;  // convert log2-unit total back to natural units

    // wave64 butterfly reduce
    #pragma unroll
    for (int off = 32; off > 0; off >>= 1)
        acc += __shfl_down(acc, off, 64);

    __shared__ float wsum[4];
    if (lane == 0) wsum[wid] = acc;
    __syncthreads();
    if (tid == 0) {
        float s = wsum[0] + wsum[1] + wsum[2] + wsum[3];
        atomicAdd(out, s);
    }
}

extern "C" void kernel_launch(void* const* d_in, const int* in_sizes, int n_in,
                              void* d_out, int out_size, void* d_ws, size_t ws_size,
                              hipStream_t stream) {
    const float* AB = (const float*)d_in[0];  // vol_AB
    const float* BA = (const float*)d_in[1];  // vol_BA
    const float* BC = (const float*)d_in[2];  // vol_BC
    const float* CB = (const float*)d_in[3];  // vol_CB
    const float* AC = (const float*)d_in[4];  // vol_AC
    const float* CA = (const float*)d_in[5];  // vol_CA
    // d_in[6..8] (xy/yz/xz rel ids) are unused by the reference.

    const unsigned nElems = (unsigned)in_sizes[0];  // N*2 = 16M
    const int block = 256;
    // 72 KB LDS/block -> 2 blocks/CU resident; grid 512 = exactly 2/CU
    // persistent; ~30.5 tiles per block, strided so the whole GPU sweeps
    // the arrays coherently (keeps the ~50% L3 hit rate seen in R4/R7).
    const int grid = 512;
    const size_t ldsBytes = 3u * 6u * 4u * 256u * sizeof(float);  // 72 KB

    // d_out is poisoned with 0xAA before every timed launch — zero it.
    hipMemsetAsync(d_out, 0, (size_t)out_size * sizeof(float), stream);
    box_loss_kernel<<<grid, block, ldsBytes, stream>>>(AB, BA, BC, CB, AC, CA,
                                                       (float*)d_out, nElems);
}